// Round 5
// baseline (282.437 us; speedup 1.0000x reference)
//
#include <hip/hip_runtime.h>
#include <math.h>

#define DH 128

typedef short short8 __attribute__((ext_vector_type(8)));
typedef float f32x4 __attribute__((ext_vector_type(4)));

__device__ __forceinline__ unsigned short f2bu(float f) {
  unsigned int u = __builtin_bit_cast(unsigned int, f);
  unsigned int r = (u + 0x7fffu + ((u >> 16) & 1u)) >> 16;
  return (unsigned short)r;
}
__device__ __forceinline__ float blo(unsigned int u) {
  return __builtin_bit_cast(float, u << 16);
}
__device__ __forceinline__ float bhi(unsigned int u) {
  return __builtin_bit_cast(float, u & 0xffff0000u);
}
__device__ __forceinline__ unsigned int packb2(float a, float b) {
  return (unsigned int)f2bu(a) | ((unsigned int)f2bu(b) << 16);
}

// ---------------- prep: weight transposes (fp32 [K][128] -> bf16 [128][K]) + zeroing ----------------

__global__ __launch_bounds__(256) void prep_kernel(
    const float* __restrict__ w_in, const float* __restrict__ w_gcn,
    const float* __restrict__ w_nc1, const float* __restrict__ w_oc1,
    unsigned short* __restrict__ w_inT, unsigned short* __restrict__ w_gcnT,
    unsigned short* __restrict__ w_nc1T, unsigned short* __restrict__ w_oc1T,
    int* __restrict__ cnt, float* __restrict__ out_err, int n) {
  int idx = blockIdx.x * 256 + threadIdx.x;
  if (idx < 32768) {  // w_in: K=256
    int k = idx >> 7, c = idx & 127;
    w_inT[c * 256 + k] = f2bu(w_in[idx]);
  } else if (idx < 81920) {  // 3 gcn layers
    int sub = idx - 32768;
    int off = sub & 16383;
    int k = off >> 7, c = off & 127;
    w_gcnT[(sub >> 14) * 16384 + c * 128 + k] = f2bu(w_gcn[sub]);
  } else if (idx < 98304) {
    int off = idx - 81920;
    int k = off >> 7, c = off & 127;
    w_nc1T[c * 128 + k] = f2bu(w_nc1[off]);
  } else if (idx < 114688) {
    int off = idx - 98304;
    int k = off >> 7, c = off & 127;
    w_oc1T[c * 128 + k] = f2bu(w_oc1[off]);
  } else if (idx < 114688 + n) {
    cnt[idx - 114688] = 0;
  } else if (idx < 114688 + 5 * n) {
    out_err[idx - 114688 - n] = 0.f;
  }
}

// ---------------- CSR build ----------------

__global__ void count_kernel(const int* __restrict__ col, int* __restrict__ cnt,
                             int* __restrict__ rank, int e) {
  int i = blockIdx.x * blockDim.x + threadIdx.x;
  if (i < e) rank[i] = atomicAdd(&cnt[col[i]], 1);
}

__global__ __launch_bounds__(1024) void scan1_kernel(const int* __restrict__ cnt,
                                                     int* __restrict__ rowptr,
                                                     float* __restrict__ dinv,
                                                     int* __restrict__ bsum, int n) {
  __shared__ int wsum[16];
  const int t = threadIdx.x;
  const int lane = t & 63, wid = t >> 6;
  const int i = blockIdx.x * 1024 + t;
  int v = (i < n) ? cnt[i] : 0;
  int s = v;
#pragma unroll
  for (int d = 1; d < 64; d <<= 1) {
    int u = __shfl_up(s, d);
    if (lane >= d) s += u;
  }
  if (lane == 63) wsum[wid] = s;
  __syncthreads();
  if (t < 16) {
    int ws = wsum[t];
#pragma unroll
    for (int d = 1; d < 16; d <<= 1) {
      int u = __shfl_up(ws, d);
      if (t >= d) ws += u;
    }
    wsum[t] = ws;
  }
  __syncthreads();
  if (i < n) {
    rowptr[i] = (wid ? wsum[wid - 1] : 0) + s - v;
    dinv[i] = rsqrtf((float)(v + 1));
  }
  if (t == 0) bsum[blockIdx.x] = wsum[15];
}

__global__ __launch_bounds__(256) void scan3_kernel(int* __restrict__ rowptr,
                                                    const int* __restrict__ bsum,
                                                    int n, int nb) {
  __shared__ int pre[64];
  int total = 0;
  if (threadIdx.x < 64) {
    int v = (threadIdx.x < nb) ? bsum[threadIdx.x] : 0;
    int s = v;
#pragma unroll
    for (int d = 1; d < 64; d <<= 1) {
      int u = __shfl_up(s, d);
      if ((threadIdx.x & 63) >= d) s += u;
    }
    pre[threadIdx.x] = s - v;  // exclusive
    total = s;
  }
  __syncthreads();
  int i = blockIdx.x * 256 + threadIdx.x;
  if (i < n) rowptr[i] += pre[i >> 10];
  if (blockIdx.x == 0 && threadIdx.x == 63) rowptr[n] = total;
}

__global__ void fill_kernel(const int* __restrict__ row, const int* __restrict__ col,
                            const int* __restrict__ rowptr, const int* __restrict__ rank,
                            int* __restrict__ csr, int e) {
  int i = blockIdx.x * blockDim.x + threadIdx.x;
  if (i < e) csr[rowptr[col[i]] + rank[i]] = row[i];
}

// ---------------- bf16 MFMA GEMM: C[n,128] = A[n,K] @ W[K,128] ----------------
// 64-row tile, 4 waves (2 row x 2 col), register double-buffer prefetch.
// MODE 0: store bf16 scaled by dscale[row]. MODE 1: bias+relu, store fp32 + bf16.

template <int K, bool A_FP32, int MODE>
__global__ __launch_bounds__(256) void gemm_kernel(const void* __restrict__ A_,
                                                   const unsigned short* __restrict__ WT,
                                                   const float* __restrict__ bias,
                                                   const float* __restrict__ dscale,
                                                   float* __restrict__ Cf,
                                                   unsigned short* __restrict__ Cb, int n) {
  const int t = threadIdx.x;
  const int lane = t & 63;
  const int w = t >> 6;
  const int wr = w >> 1, wc = w & 1;
  const int lr = lane & 15, lg = lane >> 4;
  const int r_base = blockIdx.x * 64 + wr * 32;
  const int c_base = wc * 64;
  constexpr int NK = K / 32;

  f32x4 acc[2][4] = {};
  short8 abuf[2][2], bbuf[2][4];

  auto load_ab = [&](int kk, short8(&av)[2], short8(&bv)[4]) {
    const int koff = kk * 32 + lg * 8;
#pragma unroll
    for (int m = 0; m < 2; m++) {
      int row = r_base + m * 16 + lr;
      row = row < n ? row : n - 1;
      if (A_FP32) {
        const float* Af = (const float*)A_;
        float4 p = *(const float4*)&Af[(size_t)row * K + koff];
        float4 q = *(const float4*)&Af[(size_t)row * K + koff + 4];
        short8 x;
        x[0] = (short)f2bu(p.x); x[1] = (short)f2bu(p.y);
        x[2] = (short)f2bu(p.z); x[3] = (short)f2bu(p.w);
        x[4] = (short)f2bu(q.x); x[5] = (short)f2bu(q.y);
        x[6] = (short)f2bu(q.z); x[7] = (short)f2bu(q.w);
        av[m] = x;
      } else {
        const unsigned short* Ab = (const unsigned short*)A_;
        av[m] = *(const short8*)&Ab[(size_t)row * K + koff];
      }
    }
#pragma unroll
    for (int nb = 0; nb < 4; nb++) {
      int col = c_base + nb * 16 + lr;
      bv[nb] = *(const short8*)&WT[(size_t)col * K + koff];
    }
  };

  load_ab(0, abuf[0], bbuf[0]);
#pragma unroll
  for (int kk = 0; kk < NK; kk++) {
    const int cur = kk & 1, nxt = cur ^ 1;
    if (kk + 1 < NK) load_ab(kk + 1, abuf[nxt], bbuf[nxt]);
#pragma unroll
    for (int m = 0; m < 2; m++)
#pragma unroll
      for (int nb = 0; nb < 4; nb++)
        acc[m][nb] =
            __builtin_amdgcn_mfma_f32_16x16x32_bf16(abuf[cur][m], bbuf[cur][nb], acc[m][nb], 0, 0, 0);
  }

  float bcol[4];
  if (MODE != 0) {
#pragma unroll
    for (int nb = 0; nb < 4; nb++) bcol[nb] = bias[c_base + nb * 16 + lr];
  }

#pragma unroll
  for (int m = 0; m < 2; m++) {
#pragma unroll
    for (int i = 0; i < 4; i++) {
      int row = r_base + m * 16 + lg * 4 + i;
      if (row < n) {
        float sc = (MODE == 0) ? dscale[row] : 0.f;
#pragma unroll
        for (int nb = 0; nb < 4; nb++) {
          int col = c_base + nb * 16 + lr;
          float v = acc[m][nb][i];
          if (MODE == 0) {
            Cb[(size_t)row * DH + col] = f2bu(v * sc);
          } else {
            v = fmaxf(v + bcol[nb], 0.f);
            Cf[(size_t)row * DH + col] = v;
            Cb[(size_t)row * DH + col] = f2bu(v);
          }
        }
      }
    }
  }
}

// ---------------- aggregation: h = relu(h + self * sum(xwb') + b) ----------------
// xwb' rows pre-scaled by dinv[src]; pure gather-add; 16-edge (8/half-wave) pipeline.

__global__ __launch_bounds__(256) void agg_kernel(const uint2* __restrict__ xwb2,
                                                  const float* __restrict__ dinv,
                                                  const int* __restrict__ rowptr,
                                                  const int* __restrict__ csr,
                                                  const float* __restrict__ bias,
                                                  float* __restrict__ h,
                                                  uint2* __restrict__ hb2, int n) {
  const int node = blockIdx.x * 4 + (threadIdx.x >> 6);
  if (node >= n) return;
  const int lane = threadIdx.x & 63;
  const int half = lane >> 5;
  const int cidx = lane & 31;
  const float self = dinv[node];

  float a0, a1, a2, a3;
  if (half == 0) {  // self loop counted once
    uint2 su = xwb2[(size_t)node * 32 + cidx];
    a0 = blo(su.x); a1 = bhi(su.x);
    a2 = blo(su.y); a3 = bhi(su.y);
  } else {
    a0 = a1 = a2 = a3 = 0.f;
  }

  const int beg = rowptr[node], end = rowptr[node + 1];
  int j = beg;
  for (; j + 16 <= end; j += 16) {
    int s[8];
#pragma unroll
    for (int k = 0; k < 8; k++) s[k] = csr[j + 2 * k + half];
    uint2 u[8];
#pragma unroll
    for (int k = 0; k < 8; k++) u[k] = xwb2[(size_t)s[k] * 32 + cidx];
#pragma unroll
    for (int k = 0; k < 8; k++) {
      a0 += blo(u[k].x); a1 += bhi(u[k].x);
      a2 += blo(u[k].y); a3 += bhi(u[k].y);
    }
  }
  for (; j + 8 <= end; j += 8) {
    int s0 = csr[j + half], s1 = csr[j + 2 + half];
    int s2 = csr[j + 4 + half], s3 = csr[j + 6 + half];
    uint2 u0 = xwb2[(size_t)s0 * 32 + cidx];
    uint2 u1 = xwb2[(size_t)s1 * 32 + cidx];
    uint2 u2 = xwb2[(size_t)s2 * 32 + cidx];
    uint2 u3 = xwb2[(size_t)s3 * 32 + cidx];
    a0 += blo(u0.x); a1 += bhi(u0.x); a2 += blo(u0.y); a3 += bhi(u0.y);
    a0 += blo(u1.x); a1 += bhi(u1.x); a2 += blo(u1.y); a3 += bhi(u1.y);
    a0 += blo(u2.x); a1 += bhi(u2.x); a2 += blo(u2.y); a3 += bhi(u2.y);
    a0 += blo(u3.x); a1 += bhi(u3.x); a2 += blo(u3.y); a3 += bhi(u3.y);
  }
  for (; j < end; j += 2) {
    int jj = j + half;
    if (jj < end) {
      int s = csr[jj];
      uint2 u = xwb2[(size_t)s * 32 + cidx];
      a0 += blo(u.x); a1 += bhi(u.x); a2 += blo(u.y); a3 += bhi(u.y);
    }
  }

  a0 += __shfl_xor(a0, 32);
  a1 += __shfl_xor(a1, 32);
  a2 += __shfl_xor(a2, 32);
  a3 += __shfl_xor(a3, 32);

  if (half == 0) {
    const float4 bv = *(const float4*)&bias[cidx * 4];
    const float4 hv = *(const float4*)&h[(size_t)node * DH + cidx * 4];
    float r0 = fmaxf(hv.x + self * a0 + bv.x, 0.f);
    float r1 = fmaxf(hv.y + self * a1 + bv.y, 0.f);
    float r2 = fmaxf(hv.z + self * a2 + bv.z, 0.f);
    float r3 = fmaxf(hv.w + self * a3 + bv.w, 0.f);
    *(float4*)&h[(size_t)node * DH + cidx * 4] = make_float4(r0, r1, r2, r3);
    hb2[(size_t)node * 32 + cidx] = make_uint2(packb2(r0, r1), packb2(r2, r3));
  }
}

// ---------------- fused dual MLP head (64-row tile, shared A load) ----------------

__global__ __launch_bounds__(256) void heads_kernel(
    const unsigned short* __restrict__ hb,
    const unsigned short* __restrict__ w1T_a, const float* __restrict__ b1_a,
    const float* __restrict__ w2_a, const float* __restrict__ b2_a,
    const unsigned short* __restrict__ w1T_b, const float* __restrict__ b1_b,
    const float* __restrict__ w2_b, const float* __restrict__ b2_b,
    float* __restrict__ out_a, float* __restrict__ out_b, int n) {
  const int t = threadIdx.x;
  const int lane = t & 63;
  const int w = t >> 6;
  const int lr = lane & 15, lg = lane >> 4;
  const int r_base = blockIdx.x * 64 + w * 16;

  f32x4 acc[2][8] = {};  // [head][nb]
#pragma unroll
  for (int kk = 0; kk < 4; kk++) {
    const int koff = kk * 32 + lg * 8;
    int row = r_base + lr;
    row = row < n ? row : n - 1;
    short8 a = *(const short8*)&hb[(size_t)row * DH + koff];
#pragma unroll
    for (int nb = 0; nb < 8; nb++) {
      short8 ba = *(const short8*)&w1T_a[(size_t)(nb * 16 + lr) * DH + koff];
      short8 bb = *(const short8*)&w1T_b[(size_t)(nb * 16 + lr) * DH + koff];
      acc[0][nb] = __builtin_amdgcn_mfma_f32_16x16x32_bf16(a, ba, acc[0][nb], 0, 0, 0);
      acc[1][nb] = __builtin_amdgcn_mfma_f32_16x16x32_bf16(a, bb, acc[1][nb], 0, 0, 0);
    }
  }

#pragma unroll
  for (int head = 0; head < 2; head++) {
    const float* b1 = head ? b1_b : b1_a;
    const float* w2 = head ? w2_b : w2_a;
    const float b2 = head ? b2_b[0] : b2_a[0];
    float* out = head ? out_b : out_a;

    float b1v[8], w2v[8];
#pragma unroll
    for (int nb = 0; nb < 8; nb++) {
      b1v[nb] = b1[nb * 16 + lr];
      w2v[nb] = w2[nb * 16 + lr];
    }

#pragma unroll
    for (int i = 0; i < 4; i++) {
      float s = 0.f;
#pragma unroll
      for (int nb = 0; nb < 8; nb++)
        s += fmaxf(acc[head][nb][i] + b1v[nb], 0.f) * w2v[nb];
      s += __shfl_xor(s, 1);
      s += __shfl_xor(s, 2);
      s += __shfl_xor(s, 4);
      s += __shfl_xor(s, 8);
      int row = r_base + lg * 4 + i;
      if (lr == 0 && row < n) out[row] = 1.f / (1.f + __expf(-(s + b2)));
    }
  }
}

// ---------------- launch ----------------

extern "C" void kernel_launch(void* const* d_in, const int* in_sizes, int n_in,
                              void* d_out, int out_size, void* d_ws, size_t ws_size,
                              hipStream_t stream) {
  const float* x     = (const float*)d_in[0];
  const int*   ei    = (const int*)d_in[1];
  const float* w_in  = (const float*)d_in[2];
  const float* b_in  = (const float*)d_in[3];
  const float* w_gcn = (const float*)d_in[4];
  const float* b_gcn = (const float*)d_in[5];
  const float* w_nc1 = (const float*)d_in[6];
  const float* b_nc1 = (const float*)d_in[7];
  const float* w_nc2 = (const float*)d_in[8];
  const float* b_nc2 = (const float*)d_in[9];
  const float* w_oc1 = (const float*)d_in[10];
  const float* b_oc1 = (const float*)d_in[11];
  const float* w_oc2 = (const float*)d_in[12];
  const float* b_oc2 = (const float*)d_in[13];

  const int N = in_sizes[0] / 256;  // 50000
  const int E = in_sizes[1] / 2;    // 600000
  const int* erow = ei;
  const int* ecol = ei + E;

  float* out      = (float*)d_out;
  float* out_node = out;
  float* out_orig = out + N;
  float* out_err  = out + 2 * (size_t)N;
  float* h        = out + 6 * (size_t)N;  // final h lives directly in d_out

  // workspace carve
  unsigned short* xwb = (unsigned short*)d_ws;            // N*128 bf16
  unsigned short* hb  = xwb + (size_t)N * DH;             // N*128 bf16
  unsigned short* w_inT  = hb + (size_t)N * DH;           // 128 x 256
  unsigned short* w_gcnT = w_inT + 128 * 256;             // 3 x 128 x 128
  unsigned short* w_nc1T = w_gcnT + 3 * 128 * 128;
  unsigned short* w_oc1T = w_nc1T + 128 * 128;
  float* dinv = (float*)(w_oc1T + 128 * 128);             // N
  int* cnt    = (int*)(dinv + N);                         // N
  int* rowptr = cnt + N;                                  // N+1
  int* bsum   = rowptr + N + 1;                           // 64
  int* rank   = bsum + 64;                                // E
  int* csr    = rank + E;                                 // E

  prep_kernel<<<(114688 + 5 * N + 255) / 256, 256, 0, stream>>>(
      w_in, w_gcn, w_nc1, w_oc1, w_inT, w_gcnT, w_nc1T, w_oc1T, cnt, out_err, N);

  const int eb = (E + 255) / 256;
  count_kernel<<<eb, 256, 0, stream>>>(ecol, cnt, rank, E);
  const int nb1 = (N + 1023) / 1024;
  scan1_kernel<<<nb1, 1024, 0, stream>>>(cnt, rowptr, dinv, bsum, N);
  scan3_kernel<<<(N + 255) / 256, 256, 0, stream>>>(rowptr, bsum, N, nb1);
  fill_kernel<<<eb, 256, 0, stream>>>(erow, ecol, rowptr, rank, csr, E);

  const int mb = (N + 63) / 64;
  // h = relu(x @ w_in + b_in), also hb = bf16(h)
  gemm_kernel<256, true, 1><<<mb, 256, 0, stream>>>(x, w_inT, b_in, nullptr, h, hb, N);
  // 3 GCN layers: xwb = dinv * (hb @ W); h = relu(h + dinv*sum(xwb) + b)
  for (int l = 0; l < 3; l++) {
    gemm_kernel<128, false, 0><<<mb, 256, 0, stream>>>(hb, w_gcnT + (size_t)l * DH * DH,
                                                       nullptr, dinv, nullptr, xwb, N);
    agg_kernel<<<(N + 3) / 4, 256, 0, stream>>>((const uint2*)xwb, dinv, rowptr, csr,
                                                b_gcn + (size_t)l * DH, h,
                                                (uint2*)hb, N);
  }
  // fused heads
  heads_kernel<<<mb, 256, 0, stream>>>(hb, w_nc1T, b_nc1, w_nc2, b_nc2,
                                       w_oc1T, b_oc1, w_oc2, b_oc2,
                                       out_node, out_orig, N);
}

// Round 6
// 277.786 us; speedup vs baseline: 1.0167x; 1.0167x over previous
//
#include <hip/hip_runtime.h>
#include <math.h>

#define DH 128

typedef short short8 __attribute__((ext_vector_type(8)));
typedef float f32x4 __attribute__((ext_vector_type(4)));

__device__ __forceinline__ unsigned short f2bu(float f) {
  unsigned int u = __builtin_bit_cast(unsigned int, f);
  unsigned int r = (u + 0x7fffu + ((u >> 16) & 1u)) >> 16;
  return (unsigned short)r;
}
__device__ __forceinline__ float blo(unsigned int u) {
  return __builtin_bit_cast(float, u << 16);
}
__device__ __forceinline__ float bhi(unsigned int u) {
  return __builtin_bit_cast(float, u & 0xffff0000u);
}
__device__ __forceinline__ unsigned int packb2(float a, float b) {
  return (unsigned int)f2bu(a) | ((unsigned int)f2bu(b) << 16);
}
// swizzled LDS index (floats): xor bits 2-4 of col with row&7 -> 16B-granular swizzle
__device__ __forceinline__ int sidx(int w, int r, int c) {
  return w * 2048 + r * 128 + (c ^ ((r & 7) << 2));
}

// ---------------- prep: weight transposes (fp32 [K][128] -> bf16 [128][K]) + zeroing ----------------

__global__ __launch_bounds__(256) void prep_kernel(
    const float* __restrict__ w_in, const float* __restrict__ w_gcn,
    const float* __restrict__ w_nc1, const float* __restrict__ w_oc1,
    unsigned short* __restrict__ w_inT, unsigned short* __restrict__ w_gcnT,
    unsigned short* __restrict__ w_nc1T, unsigned short* __restrict__ w_oc1T,
    int* __restrict__ cnt, float* __restrict__ out_err, int n) {
  int idx = blockIdx.x * 256 + threadIdx.x;
  if (idx < 32768) {  // w_in: K=256
    int k = idx >> 7, c = idx & 127;
    w_inT[c * 256 + k] = f2bu(w_in[idx]);
  } else if (idx < 81920) {  // 3 gcn layers
    int sub = idx - 32768;
    int off = sub & 16383;
    int k = off >> 7, c = off & 127;
    w_gcnT[(sub >> 14) * 16384 + c * 128 + k] = f2bu(w_gcn[sub]);
  } else if (idx < 98304) {
    int off = idx - 81920;
    int k = off >> 7, c = off & 127;
    w_nc1T[c * 128 + k] = f2bu(w_nc1[off]);
  } else if (idx < 114688) {
    int off = idx - 98304;
    int k = off >> 7, c = off & 127;
    w_oc1T[c * 128 + k] = f2bu(w_oc1[off]);
  } else if (idx < 114688 + n) {
    cnt[idx - 114688] = 0;
  } else if (idx < 114688 + 5 * n) {
    out_err[idx - 114688 - n] = 0.f;
  }
}

// ---------------- CSR build ----------------

__global__ void count_kernel(const int* __restrict__ col, int* __restrict__ cnt,
                             int* __restrict__ rank, int e) {
  int i = blockIdx.x * blockDim.x + threadIdx.x;
  if (i < e) rank[i] = atomicAdd(&cnt[col[i]], 1);
}

__global__ __launch_bounds__(1024) void scan1_kernel(const int* __restrict__ cnt,
                                                     int* __restrict__ rowptr,
                                                     float* __restrict__ dinv,
                                                     int* __restrict__ bsum, int n) {
  __shared__ int wsum[16];
  const int t = threadIdx.x;
  const int lane = t & 63, wid = t >> 6;
  const int i = blockIdx.x * 1024 + t;
  int v = (i < n) ? cnt[i] : 0;
  int s = v;
#pragma unroll
  for (int d = 1; d < 64; d <<= 1) {
    int u = __shfl_up(s, d);
    if (lane >= d) s += u;
  }
  if (lane == 63) wsum[wid] = s;
  __syncthreads();
  if (t < 16) {
    int ws = wsum[t];
#pragma unroll
    for (int d = 1; d < 16; d <<= 1) {
      int u = __shfl_up(ws, d);
      if (t >= d) ws += u;
    }
    wsum[t] = ws;
  }
  __syncthreads();
  if (i < n) {
    rowptr[i] = (wid ? wsum[wid - 1] : 0) + s - v;
    dinv[i] = rsqrtf((float)(v + 1));
  }
  if (t == 0) bsum[blockIdx.x] = wsum[15];
}

__global__ __launch_bounds__(256) void scan3_kernel(int* __restrict__ rowptr,
                                                    const int* __restrict__ bsum,
                                                    int n, int nb) {
  __shared__ int pre[64];
  int total = 0;
  if (threadIdx.x < 64) {
    int v = (threadIdx.x < nb) ? bsum[threadIdx.x] : 0;
    int s = v;
#pragma unroll
    for (int d = 1; d < 64; d <<= 1) {
      int u = __shfl_up(s, d);
      if ((threadIdx.x & 63) >= d) s += u;
    }
    pre[threadIdx.x] = s - v;  // exclusive
    total = s;
  }
  __syncthreads();
  int i = blockIdx.x * 256 + threadIdx.x;
  if (i < n) rowptr[i] += pre[i >> 10];
  if (blockIdx.x == 0 && threadIdx.x == 63) rowptr[n] = total;
}

__global__ void fill_kernel(const int* __restrict__ row, const int* __restrict__ col,
                            const int* __restrict__ rowptr, const int* __restrict__ rank,
                            int* __restrict__ csr, int e) {
  int i = blockIdx.x * blockDim.x + threadIdx.x;
  if (i < e) csr[rowptr[col[i]] + rank[i]] = row[i];
}

// ---------------- K-split bf16 MFMA GEMM: C[n,128] = A[n,K] @ W[K,128] ----------------
// Block: 16 rows x 128 cols; 4 waves each own K-slice(s) of 32; LDS reduce.
// MODE 0: store bf16 scaled by dscale[row]. MODE 1: bias+relu, store fp32 + bf16.

template <int K, bool A_FP32, int MODE>
__global__ __launch_bounds__(256) void gemm_kernel(const void* __restrict__ A_,
                                                   const unsigned short* __restrict__ WT,
                                                   const float* __restrict__ bias,
                                                   const float* __restrict__ dscale,
                                                   float* __restrict__ Cf,
                                                   unsigned short* __restrict__ Cb, int n) {
  __shared__ float red[4 * 2048];  // 32 KB
  const int t = threadIdx.x;
  const int lane = t & 63;
  const int w = t >> 6;
  const int lr = lane & 15, lg = lane >> 4;
  const int r0 = blockIdx.x * 16;
  constexpr int S = K / 128;  // k-slices per wave

  f32x4 acc[8] = {};
#pragma unroll
  for (int s = 0; s < S; s++) {
    const int koff = (w + s * 4) * 32 + lg * 8;
    int row = r0 + lr;
    row = row < n ? row : n - 1;
    short8 a;
    if (A_FP32) {
      const float* Af = (const float*)A_;
      float4 p = *(const float4*)&Af[(size_t)row * K + koff];
      float4 q = *(const float4*)&Af[(size_t)row * K + koff + 4];
      a[0] = (short)f2bu(p.x); a[1] = (short)f2bu(p.y);
      a[2] = (short)f2bu(p.z); a[3] = (short)f2bu(p.w);
      a[4] = (short)f2bu(q.x); a[5] = (short)f2bu(q.y);
      a[6] = (short)f2bu(q.z); a[7] = (short)f2bu(q.w);
    } else {
      const unsigned short* Ab = (const unsigned short*)A_;
      a = *(const short8*)&Ab[(size_t)row * K + koff];
    }
    short8 b[8];
#pragma unroll
    for (int nb = 0; nb < 8; nb++)
      b[nb] = *(const short8*)&WT[(size_t)(nb * 16 + lr) * K + koff];
#pragma unroll
    for (int nb = 0; nb < 8; nb++)
      acc[nb] = __builtin_amdgcn_mfma_f32_16x16x32_bf16(a, b[nb], acc[nb], 0, 0, 0);
  }

  // partial sums -> LDS (swizzled)
#pragma unroll
  for (int nb = 0; nb < 8; nb++)
#pragma unroll
    for (int i = 0; i < 4; i++)
      red[sidx(w, lg * 4 + i, nb * 16 + lr)] = acc[nb][i];
  __syncthreads();

  // epilogue: thread t -> row t>>4, cols (t&15)*8 .. +8 (lanes 0-15 = one row: coalesced)
  const int row = t >> 4;
  const int c0 = (t & 15) * 8;
  const int gr = r0 + row;
  float v[8];
#pragma unroll
  for (int q = 0; q < 2; q++) {
    const int cb = (c0 + 4 * q) ^ ((row & 7) << 2);
    const int base = row * 128 + cb;
    float4 s0 = *(const float4*)&red[base];
    float4 s1 = *(const float4*)&red[2048 + base];
    float4 s2 = *(const float4*)&red[4096 + base];
    float4 s3 = *(const float4*)&red[6144 + base];
    v[4 * q + 0] = s0.x + s1.x + s2.x + s3.x;
    v[4 * q + 1] = s0.y + s1.y + s2.y + s3.y;
    v[4 * q + 2] = s0.z + s1.z + s2.z + s3.z;
    v[4 * q + 3] = s0.w + s1.w + s2.w + s3.w;
  }

  if (gr < n) {
    if (MODE == 0) {
      const float sc = dscale[gr];
      uint4 o;
      o.x = packb2(v[0] * sc, v[1] * sc);
      o.y = packb2(v[2] * sc, v[3] * sc);
      o.z = packb2(v[4] * sc, v[5] * sc);
      o.w = packb2(v[6] * sc, v[7] * sc);
      *(uint4*)&Cb[(size_t)gr * DH + c0] = o;
    } else {
      float4 b0 = *(const float4*)&bias[c0];
      float4 b1 = *(const float4*)&bias[c0 + 4];
      float r0f = fmaxf(v[0] + b0.x, 0.f), r1f = fmaxf(v[1] + b0.y, 0.f);
      float r2f = fmaxf(v[2] + b0.z, 0.f), r3f = fmaxf(v[3] + b0.w, 0.f);
      float r4f = fmaxf(v[4] + b1.x, 0.f), r5f = fmaxf(v[5] + b1.y, 0.f);
      float r6f = fmaxf(v[6] + b1.z, 0.f), r7f = fmaxf(v[7] + b1.w, 0.f);
      *(float4*)&Cf[(size_t)gr * DH + c0] = make_float4(r0f, r1f, r2f, r3f);
      *(float4*)&Cf[(size_t)gr * DH + c0 + 4] = make_float4(r4f, r5f, r6f, r7f);
      uint4 o;
      o.x = packb2(r0f, r1f); o.y = packb2(r2f, r3f);
      o.z = packb2(r4f, r5f); o.w = packb2(r6f, r7f);
      *(uint4*)&Cb[(size_t)gr * DH + c0] = o;
    }
  }
}

// ---------------- aggregation: h = relu(h + self * sum(xwb') + b) ----------------
// xwb' rows pre-scaled by dinv[src]; pure gather-add; 16-edge (8/half-wave) pipeline.

__global__ __launch_bounds__(256) void agg_kernel(const uint2* __restrict__ xwb2,
                                                  const float* __restrict__ dinv,
                                                  const int* __restrict__ rowptr,
                                                  const int* __restrict__ csr,
                                                  const float* __restrict__ bias,
                                                  float* __restrict__ h,
                                                  uint2* __restrict__ hb2, int n) {
  const int node = blockIdx.x * 4 + (threadIdx.x >> 6);
  if (node >= n) return;
  const int lane = threadIdx.x & 63;
  const int half = lane >> 5;
  const int cidx = lane & 31;
  const float self = dinv[node];

  float a0, a1, a2, a3;
  if (half == 0) {  // self loop counted once
    uint2 su = xwb2[(size_t)node * 32 + cidx];
    a0 = blo(su.x); a1 = bhi(su.x);
    a2 = blo(su.y); a3 = bhi(su.y);
  } else {
    a0 = a1 = a2 = a3 = 0.f;
  }

  const int beg = rowptr[node], end = rowptr[node + 1];
  int j = beg;
  for (; j + 16 <= end; j += 16) {
    int s[8];
#pragma unroll
    for (int k = 0; k < 8; k++) s[k] = csr[j + 2 * k + half];
    uint2 u[8];
#pragma unroll
    for (int k = 0; k < 8; k++) u[k] = xwb2[(size_t)s[k] * 32 + cidx];
#pragma unroll
    for (int k = 0; k < 8; k++) {
      a0 += blo(u[k].x); a1 += bhi(u[k].x);
      a2 += blo(u[k].y); a3 += bhi(u[k].y);
    }
  }
  for (; j + 8 <= end; j += 8) {
    int s0 = csr[j + half], s1 = csr[j + 2 + half];
    int s2 = csr[j + 4 + half], s3 = csr[j + 6 + half];
    uint2 u0 = xwb2[(size_t)s0 * 32 + cidx];
    uint2 u1 = xwb2[(size_t)s1 * 32 + cidx];
    uint2 u2 = xwb2[(size_t)s2 * 32 + cidx];
    uint2 u3 = xwb2[(size_t)s3 * 32 + cidx];
    a0 += blo(u0.x); a1 += bhi(u0.x); a2 += blo(u0.y); a3 += bhi(u0.y);
    a0 += blo(u1.x); a1 += bhi(u1.x); a2 += blo(u1.y); a3 += bhi(u1.y);
    a0 += blo(u2.x); a1 += bhi(u2.x); a2 += blo(u2.y); a3 += bhi(u2.y);
    a0 += blo(u3.x); a1 += bhi(u3.x); a2 += blo(u3.y); a3 += bhi(u3.y);
  }
  for (; j < end; j += 2) {
    int jj = j + half;
    if (jj < end) {
      int s = csr[jj];
      uint2 u = xwb2[(size_t)s * 32 + cidx];
      a0 += blo(u.x); a1 += bhi(u.x); a2 += blo(u.y); a3 += bhi(u.y);
    }
  }

  a0 += __shfl_xor(a0, 32);
  a1 += __shfl_xor(a1, 32);
  a2 += __shfl_xor(a2, 32);
  a3 += __shfl_xor(a3, 32);

  if (half == 0) {
    const float4 bv = *(const float4*)&bias[cidx * 4];
    const float4 hv = *(const float4*)&h[(size_t)node * DH + cidx * 4];
    float r0 = fmaxf(hv.x + self * a0 + bv.x, 0.f);
    float r1 = fmaxf(hv.y + self * a1 + bv.y, 0.f);
    float r2 = fmaxf(hv.z + self * a2 + bv.z, 0.f);
    float r3 = fmaxf(hv.w + self * a3 + bv.w, 0.f);
    *(float4*)&h[(size_t)node * DH + cidx * 4] = make_float4(r0, r1, r2, r3);
    hb2[(size_t)node * 32 + cidx] = make_uint2(packb2(r0, r1), packb2(r2, r3));
  }
}

// ---------------- fused dual MLP head (K-split, LDS reduce, shfl-16 dot) ----------------

__global__ __launch_bounds__(256) void heads_kernel(
    const unsigned short* __restrict__ hb,
    const unsigned short* __restrict__ w1T_a, const float* __restrict__ b1_a,
    const float* __restrict__ w2_a, const float* __restrict__ b2_a,
    const unsigned short* __restrict__ w1T_b, const float* __restrict__ b1_b,
    const float* __restrict__ w2_b, const float* __restrict__ b2_b,
    float* __restrict__ out_a, float* __restrict__ out_b, int n) {
  __shared__ float red[4 * 2048];
  const int t = threadIdx.x;
  const int lane = t & 63;
  const int w = t >> 6;
  const int lr = lane & 15, lg = lane >> 4;
  const int r0 = blockIdx.x * 16;
  const int koff = w * 32 + lg * 8;

  int arow = r0 + lr;
  arow = arow < n ? arow : n - 1;
  short8 a = *(const short8*)&hb[(size_t)arow * DH + koff];

  f32x4 acc0[8] = {}, acc1[8] = {};
#pragma unroll
  for (int nb = 0; nb < 8; nb++) {
    short8 ba = *(const short8*)&w1T_a[(size_t)(nb * 16 + lr) * DH + koff];
    acc0[nb] = __builtin_amdgcn_mfma_f32_16x16x32_bf16(a, ba, acc0[nb], 0, 0, 0);
  }
#pragma unroll
  for (int nb = 0; nb < 8; nb++) {
    short8 bb = *(const short8*)&w1T_b[(size_t)(nb * 16 + lr) * DH + koff];
    acc1[nb] = __builtin_amdgcn_mfma_f32_16x16x32_bf16(a, bb, acc1[nb], 0, 0, 0);
  }

  const int row = t >> 4;
  const int c0 = (t & 15) * 8;
  const int gr = r0 + row;

#pragma unroll
  for (int head = 0; head < 2; head++) {
    if (head) __syncthreads();  // protect LDS reuse
#pragma unroll
    for (int nb = 0; nb < 8; nb++)
#pragma unroll
      for (int i = 0; i < 4; i++)
        red[sidx(w, lg * 4 + i, nb * 16 + lr)] = head ? acc1[nb][i] : acc0[nb][i];
    __syncthreads();

    const float* b1 = head ? b1_b : b1_a;
    const float* w2 = head ? w2_b : w2_a;
    float partial = 0.f;
#pragma unroll
    for (int q = 0; q < 2; q++) {
      const int cb = (c0 + 4 * q) ^ ((row & 7) << 2);
      const int base = row * 128 + cb;
      float4 s0 = *(const float4*)&red[base];
      float4 s1 = *(const float4*)&red[2048 + base];
      float4 s2 = *(const float4*)&red[4096 + base];
      float4 s3 = *(const float4*)&red[6144 + base];
      float4 bv = *(const float4*)&b1[c0 + 4 * q];
      float4 wv = *(const float4*)&w2[c0 + 4 * q];
      partial += fmaxf(s0.x + s1.x + s2.x + s3.x + bv.x, 0.f) * wv.x;
      partial += fmaxf(s0.y + s1.y + s2.y + s3.y + bv.y, 0.f) * wv.y;
      partial += fmaxf(s0.z + s1.z + s2.z + s3.z + bv.z, 0.f) * wv.z;
      partial += fmaxf(s0.w + s1.w + s2.w + s3.w + bv.w, 0.f) * wv.w;
    }
    partial += __shfl_xor(partial, 1);
    partial += __shfl_xor(partial, 2);
    partial += __shfl_xor(partial, 4);
    partial += __shfl_xor(partial, 8);
    if ((t & 15) == 0 && gr < n) {
      const float b2 = head ? b2_b[0] : b2_a[0];
      float* out = head ? out_b : out_a;
      out[gr] = 1.f / (1.f + __expf(-(partial + b2)));
    }
  }
}

// ---------------- launch ----------------

extern "C" void kernel_launch(void* const* d_in, const int* in_sizes, int n_in,
                              void* d_out, int out_size, void* d_ws, size_t ws_size,
                              hipStream_t stream) {
  const float* x     = (const float*)d_in[0];
  const int*   ei    = (const int*)d_in[1];
  const float* w_in  = (const float*)d_in[2];
  const float* b_in  = (const float*)d_in[3];
  const float* w_gcn = (const float*)d_in[4];
  const float* b_gcn = (const float*)d_in[5];
  const float* w_nc1 = (const float*)d_in[6];
  const float* b_nc1 = (const float*)d_in[7];
  const float* w_nc2 = (const float*)d_in[8];
  const float* b_nc2 = (const float*)d_in[9];
  const float* w_oc1 = (const float*)d_in[10];
  const float* b_oc1 = (const float*)d_in[11];
  const float* w_oc2 = (const float*)d_in[12];
  const float* b_oc2 = (const float*)d_in[13];

  const int N = in_sizes[0] / 256;  // 50000
  const int E = in_sizes[1] / 2;    // 600000
  const int* erow = ei;
  const int* ecol = ei + E;

  float* out      = (float*)d_out;
  float* out_node = out;
  float* out_orig = out + N;
  float* out_err  = out + 2 * (size_t)N;
  float* h        = out + 6 * (size_t)N;  // final h lives directly in d_out

  // workspace carve
  unsigned short* xwb = (unsigned short*)d_ws;            // N*128 bf16
  unsigned short* hb  = xwb + (size_t)N * DH;             // N*128 bf16
  unsigned short* w_inT  = hb + (size_t)N * DH;           // 128 x 256
  unsigned short* w_gcnT = w_inT + 128 * 256;             // 3 x 128 x 128
  unsigned short* w_nc1T = w_gcnT + 3 * 128 * 128;
  unsigned short* w_oc1T = w_nc1T + 128 * 128;
  float* dinv = (float*)(w_oc1T + 128 * 128);             // N
  int* cnt    = (int*)(dinv + N);                         // N
  int* rowptr = cnt + N;                                  // N+1
  int* bsum   = rowptr + N + 1;                           // 64
  int* rank   = bsum + 64;                                // E
  int* csr    = rank + E;                                 // E

  prep_kernel<<<(114688 + 5 * N + 255) / 256, 256, 0, stream>>>(
      w_in, w_gcn, w_nc1, w_oc1, w_inT, w_gcnT, w_nc1T, w_oc1T, cnt, out_err, N);

  const int eb = (E + 255) / 256;
  count_kernel<<<eb, 256, 0, stream>>>(ecol, cnt, rank, E);
  const int nb1 = (N + 1023) / 1024;
  scan1_kernel<<<nb1, 1024, 0, stream>>>(cnt, rowptr, dinv, bsum, N);
  scan3_kernel<<<(N + 255) / 256, 256, 0, stream>>>(rowptr, bsum, N, nb1);
  fill_kernel<<<eb, 256, 0, stream>>>(erow, ecol, rowptr, rank, csr, E);

  const int gb = (N + 15) / 16;  // 3125
  // h = relu(x @ w_in + b_in), also hb = bf16(h)
  gemm_kernel<256, true, 1><<<gb, 256, 0, stream>>>(x, w_inT, b_in, nullptr, h, hb, N);
  // 3 GCN layers: xwb = dinv * (hb @ W); h = relu(h + dinv*sum(xwb) + b)
  for (int l = 0; l < 3; l++) {
    gemm_kernel<128, false, 0><<<gb, 256, 0, stream>>>(hb, w_gcnT + (size_t)l * DH * DH,
                                                       nullptr, dinv, nullptr, xwb, N);
    agg_kernel<<<(N + 3) / 4, 256, 0, stream>>>((const uint2*)xwb, dinv, rowptr, csr,
                                                b_gcn + (size_t)l * DH, h,
                                                (uint2*)hb, N);
  }
  // fused heads
  heads_kernel<<<gb, 256, 0, stream>>>(hb, w_nc1T, b_nc1, w_nc2, b_nc2,
                                       w_oc1T, b_oc1, w_oc2, b_oc2,
                                       out_node, out_orig, N);
}